// Round 1
// baseline (663.775 us; speedup 1.0000x reference)
//
#include <hip/hip_runtime.h>
#include <hip/hip_bf16.h>

typedef __attribute__((ext_vector_type(8))) short short8;
typedef __attribute__((ext_vector_type(4))) float floatx4;
typedef __hip_bfloat16 bf16;

#define DIM 768
#define NH 12
#define HD 64
#define BB 16
#define NN 640
#define BH (BB*NH)          // 192
#define MROWS (BB*NN)       // 10240
#define SCALE 0.125f

__device__ __forceinline__ floatx4 mfma16(short8 a, short8 b, floatx4 c) {
    return __builtin_amdgcn_mfma_f32_16x16x32_bf16(a, b, c, 0, 0, 0);
}

// ---------------- prep kernels ----------------

__global__ void cvt_x(const float* __restrict__ x, bf16* __restrict__ xb, int n4) {
    int i = blockIdx.x * blockDim.x + threadIdx.x;
    if (i >= n4) return;
    float4 v = ((const float4*)x)[i];
    bf16* p = xb + (size_t)i * 4;
    p[0] = __float2bfloat16(v.x);
    p[1] = __float2bfloat16(v.y);
    p[2] = __float2bfloat16(v.z);
    p[3] = __float2bfloat16(v.w);
}

// src [R][C] fp32 -> dst [C][R] bf16 ; grid (C/32, R/32), block (32,8)
__global__ void tr_cvt(const float* __restrict__ src, bf16* __restrict__ dst, int R, int C) {
    __shared__ float tile[32][33];
    int bx = blockIdx.x, by = blockIdx.y;
    int tx = threadIdx.x, ty = threadIdx.y;
    for (int j = 0; j < 4; ++j)
        tile[ty + j*8][tx] = src[(size_t)(by*32 + ty + j*8) * C + bx*32 + tx];
    __syncthreads();
    for (int j = 0; j < 4; ++j)
        dst[(size_t)(bx*32 + ty + j*8) * R + by*32 + tx] = __float2bfloat16(tile[tx][ty + j*8]);
}

// ---------------- GEMM: C = A @ B^T  (A [M][K] bf16, B [N][K] bf16) ----------------
// MODE 0: scatter into q/k/vT (bf16) + qkv bias.  MODE 1: fp32 out row-major + bias.
template<int MODE>
__global__ __launch_bounds__(256) void gemm_bt(
    const bf16* __restrict__ A, const bf16* __restrict__ B, const float* __restrict__ bias,
    int M, int N, int K,
    bf16* __restrict__ qo, bf16* __restrict__ ko, bf16* __restrict__ vTo,
    float* __restrict__ out)
{
    __shared__ __align__(16) bf16 As[128*32];
    __shared__ __align__(16) bf16 Bs[128*32];

    const int t = threadIdx.x;
    const int lane = t & 63, wave = t >> 6;
    const int l15 = lane & 15, quad = lane >> 4;
    const int wm = (wave >> 1) * 64, wn = (wave & 1) * 64;
    const int m0 = blockIdx.x * 128, n0 = blockIdx.y * 128;

    floatx4 acc[4][4];
    floatx4 zero = {0.f, 0.f, 0.f, 0.f};
    for (int i = 0; i < 4; ++i)
        for (int j = 0; j < 4; ++j)
            acc[i][j] = zero;

    for (int kk = 0; kk < K; kk += 32) {
        __syncthreads();
        // stage A,B tiles (128x32 bf16 each) : 512 chunks of 16B, 2 per thread per tile
        for (int s = 0; s < 2; ++s) {
            int cid = s * 256 + t;
            int row = cid >> 2;
            int c8  = (cid & 3) << 3;
            uint4 va = *(const uint4*)(A + (size_t)(m0 + row) * K + kk + c8);
            *(uint4*)(As + cid * 8) = va;
            uint4 vb = *(const uint4*)(B + (size_t)(n0 + row) * K + kk + c8);
            *(uint4*)(Bs + cid * 8) = vb;
        }
        __syncthreads();
        short8 af[4], bfv[4];
        for (int fm = 0; fm < 4; ++fm)
            af[fm] = *(const short8*)(As + (wm + fm*16 + l15) * 32 + quad * 8);
        for (int fn = 0; fn < 4; ++fn)
            bfv[fn] = *(const short8*)(Bs + (wn + fn*16 + l15) * 32 + quad * 8);
        for (int fm = 0; fm < 4; ++fm)
            for (int fn = 0; fn < 4; ++fn)
                acc[fm][fn] = mfma16(af[fm], bfv[fn], acc[fm][fn]);
    }

    // epilogue
    for (int fm = 0; fm < 4; ++fm) {
        for (int fn = 0; fn < 4; ++fn) {
            int n = n0 + wn + fn*16 + l15;
            float bn = bias[n];
            if (MODE == 0) {
                int which = n / DIM;
                int rem = n - which * DIM;
                int h = rem >> 6, d = rem & 63;
                for (int r = 0; r < 4; ++r) {
                    int m = m0 + wm + fm*16 + quad*4 + r;
                    int b = m / NN;
                    int tok = m - b * NN;
                    int bh = b * NH + h;
                    bf16 hv = __float2bfloat16(acc[fm][fn][r] + bn);
                    if (which == 0)      qo[((size_t)bh * NN + tok) * HD + d] = hv;
                    else if (which == 1) ko[((size_t)bh * NN + tok) * HD + d] = hv;
                    else                 vTo[((size_t)bh * HD + d) * NN + tok] = hv;
                }
            } else {
                for (int r = 0; r < 4; ++r) {
                    int m = m0 + wm + fm*16 + quad*4 + r;
                    out[(size_t)m * N + n] = acc[fm][fn][r] + bn;
                }
            }
        }
    }
}

// ---------------- fused attention ----------------
// grid (10, 192), block 256 (4 waves); wave handles 16 q rows, loops 20 key tiles of 32
__global__ __launch_bounds__(256) void attn_kernel(
    const bf16* __restrict__ q, const bf16* __restrict__ k, const bf16* __restrict__ vT,
    const float* __restrict__ w2, bf16* __restrict__ ao)
{
    const int bh = blockIdx.y;
    const int b = bh / NH, h = bh - b * NH;
    const int wave = threadIdx.x >> 6;
    const int lane = threadIdx.x & 63;
    const int l15 = lane & 15, quad = lane >> 4;
    const int qrow0 = blockIdx.x * 64 + wave * 16;

    float w0 = w2[0], w1 = w2[1];
    float wmx = fmaxf(w0, w1);
    float e0 = __expf(w0 - wmx), e1 = __expf(w1 - wmx);
    float ws0 = e0 / (e0 + e1), ws1 = 1.0f - ws0;

    const bf16* qb = q  + (size_t)bh * NN * HD;
    const bf16* kb = k  + (size_t)bh * NN * HD;
    const bf16* vb = vT + (size_t)bh * HD * NN;

    short8 aq0 = *(const short8*)(qb + (qrow0 + l15) * HD + quad * 8);
    short8 aq1 = *(const short8*)(qb + (qrow0 + l15) * HD + 32 + quad * 8);

    floatx4 zero = {0.f, 0.f, 0.f, 0.f};
    floatx4 accS[4], accR[4];
    for (int i = 0; i < 4; ++i) { accS[i] = zero; accR[i] = zero; }
    float mrow[4], lrow[4];
    for (int r = 0; r < 4; ++r) { mrow[r] = -__builtin_inff(); lrow[r] = 0.f; }

    __shared__ __align__(16) bf16 Ps[4][16*32];
    __shared__ __align__(16) bf16 Pr[4][16*32];

    for (int kt = 0; kt < 20; ++kt) {
        short8 bk0 = *(const short8*)(kb + (kt*32 + l15) * HD + quad * 8);
        short8 bk1 = *(const short8*)(kb + (kt*32 + l15) * HD + 32 + quad * 8);
        short8 bk2 = *(const short8*)(kb + (kt*32 + 16 + l15) * HD + quad * 8);
        short8 bk3 = *(const short8*)(kb + (kt*32 + 16 + l15) * HD + 32 + quad * 8);

        floatx4 s0 = zero, s1 = zero;
        s0 = mfma16(aq0, bk0, s0);
        s0 = mfma16(aq1, bk1, s0);
        s1 = mfma16(aq0, bk2, s1);
        s1 = mfma16(aq1, bk3, s1);
        for (int r = 0; r < 4; ++r) { s0[r] *= SCALE; s1[r] *= SCALE; }

        // row max across the 16 lanes of each quad group
        float mt[4];
        for (int r = 0; r < 4; ++r) mt[r] = fmaxf(s0[r], s1[r]);
        for (int msk = 1; msk < 16; msk <<= 1)
            for (int r = 0; r < 4; ++r)
                mt[r] = fmaxf(mt[r], __shfl_xor(mt[r], msk));

        float al[4], ps0[4], ps1[4], pr0[4], pr1[4], rs[4];
        for (int r = 0; r < 4; ++r) {
            float mn = fmaxf(mrow[r], mt[r]);
            al[r] = __expf(mrow[r] - mn);
            mrow[r] = mn;
            ps0[r] = __expf(s0[r] - mn);
            ps1[r] = __expf(s1[r] - mn);
            rs[r] = ps0[r] + ps1[r];
            pr0[r] = s0[r] > 0.f ? s0[r] * s0[r] : 0.f;
            pr1[r] = s1[r] > 0.f ? s1[r] * s1[r] : 0.f;
        }
        for (int msk = 1; msk < 16; msk <<= 1)
            for (int r = 0; r < 4; ++r)
                rs[r] += __shfl_xor(rs[r], msk);
        for (int r = 0; r < 4; ++r) lrow[r] = lrow[r] * al[r] + rs[r];
        for (int dt = 0; dt < 4; ++dt)
            for (int r = 0; r < 4; ++r)
                accS[dt][r] *= al[r];

        // C-frag -> A-frag transpose through per-wave LDS
        for (int r = 0; r < 4; ++r) {
            Ps[wave][(quad*4 + r) * 32 + l15]      = __float2bfloat16(ps0[r]);
            Ps[wave][(quad*4 + r) * 32 + 16 + l15] = __float2bfloat16(ps1[r]);
            Pr[wave][(quad*4 + r) * 32 + l15]      = __float2bfloat16(pr0[r]);
            Pr[wave][(quad*4 + r) * 32 + 16 + l15] = __float2bfloat16(pr1[r]);
        }
        __syncthreads();
        short8 paS = *(const short8*)(&Ps[wave][l15 * 32 + quad * 8]);
        short8 paR = *(const short8*)(&Pr[wave][l15 * 32 + quad * 8]);

        for (int dt = 0; dt < 4; ++dt) {
            short8 bv = *(const short8*)(vb + (dt*16 + l15) * NN + kt*32 + quad * 8);
            accS[dt] = mfma16(paS, bv, accS[dt]);
            accR[dt] = mfma16(paR, bv, accR[dt]);
        }
        __syncthreads();
    }

    float inv[4];
    for (int r = 0; r < 4; ++r) inv[r] = 1.0f / lrow[r];
    for (int dt = 0; dt < 4; ++dt) {
        for (int r = 0; r < 4; ++r) {
            float v = ws0 * accS[dt][r] * inv[r] + ws1 * accR[dt][r];
            int tok = qrow0 + quad*4 + r;
            ao[((size_t)(b * NN + tok)) * DIM + h * HD + dt*16 + l15] = __float2bfloat16(v);
        }
    }
}

// ---------------- launch ----------------

extern "C" void kernel_launch(void* const* d_in, const int* in_sizes, int n_in,
                              void* d_out, int out_size, void* d_ws, size_t ws_size,
                              hipStream_t stream) {
    const float* x      = (const float*)d_in[0];
    const float* qkv_w  = (const float*)d_in[1];
    const float* qkv_b  = (const float*)d_in[2];
    const float* proj_w = (const float*)d_in[3];
    const float* proj_b = (const float*)d_in[4];
    const float* w2     = (const float*)d_in[5];
    float* out = (float*)d_out;

    bf16* xb  = (bf16*)d_ws;                       // 10240*768
    bf16* qwT = xb  + (size_t)MROWS * DIM;         // 2304*768
    bf16* pwT = qwT + (size_t)3 * DIM * DIM;       // 768*768
    bf16* qq  = pwT + (size_t)DIM * DIM;           // 192*640*64
    bf16* kk  = qq  + (size_t)BH * NN * HD;
    bf16* vT  = kk  + (size_t)BH * NN * HD;
    bf16* ao  = vT  + (size_t)BH * NN * HD;        // 10240*768

    cvt_x<<<(MROWS * DIM / 4 + 255) / 256, 256, 0, stream>>>(x, xb, MROWS * DIM / 4);
    tr_cvt<<<dim3(3 * DIM / 32, DIM / 32), dim3(32, 8), 0, stream>>>(qkv_w, qwT, DIM, 3 * DIM);
    tr_cvt<<<dim3(DIM / 32, DIM / 32), dim3(32, 8), 0, stream>>>(proj_w, pwT, DIM, DIM);

    gemm_bt<0><<<dim3(MROWS / 128, 3 * DIM / 128), 256, 0, stream>>>(
        xb, qwT, qkv_b, MROWS, 3 * DIM, DIM, qq, kk, vT, nullptr);

    attn_kernel<<<dim3(NN / 64, BH), 256, 0, stream>>>(qq, kk, vT, w2, ao);

    gemm_bt<1><<<dim3(MROWS / 128, DIM / 128), 256, 0, stream>>>(
        ao, pwT, proj_b, MROWS, DIM, DIM, nullptr, nullptr, nullptr, out);
}

// Round 2
// 335.209 us; speedup vs baseline: 1.9802x; 1.9802x over previous
//
#include <hip/hip_runtime.h>
#include <hip/hip_bf16.h>

typedef __attribute__((ext_vector_type(8))) short short8;
typedef __attribute__((ext_vector_type(4))) float floatx4;
typedef __hip_bfloat16 bf16;

#define DIM 768
#define NH 12
#define HD 64
#define BB 16
#define NN 640
#define BH (BB*NH)          // 192
#define MROWS (BB*NN)       // 10240
#define QKVN (3*DIM)        // 2304
#define SCALE 0.125f

__device__ __forceinline__ floatx4 mfma16(short8 a, short8 b, floatx4 c) {
    return __builtin_amdgcn_mfma_f32_16x16x32_bf16(a, b, c, 0, 0, 0);
}

// async global->LDS, 16B per lane; lds dest = wave-uniform base + lane*16
__device__ __forceinline__ void async_ld16(const bf16* g, bf16* l) {
    __builtin_amdgcn_global_load_lds(
        (const __attribute__((address_space(1))) void*)g,
        (__attribute__((address_space(3))) void*)l, 16, 0, 0);
}

// ---------------- prep kernels ----------------

__global__ void cvt_x(const float* __restrict__ x, bf16* __restrict__ xb, int n4) {
    int i = blockIdx.x * blockDim.x + threadIdx.x;
    if (i >= n4) return;
    float4 v = ((const float4*)x)[i];
    bf16* p = xb + (size_t)i * 4;
    p[0] = __float2bfloat16(v.x);
    p[1] = __float2bfloat16(v.y);
    p[2] = __float2bfloat16(v.z);
    p[3] = __float2bfloat16(v.w);
}

// src [R][C] fp32 -> dst [C][R] bf16 ; grid (C/32, R/32), block (32,8)
__global__ void tr_cvt(const float* __restrict__ src, bf16* __restrict__ dst, int R, int C) {
    __shared__ float tile[32][33];
    int bx = blockIdx.x, by = blockIdx.y;
    int tx = threadIdx.x, ty = threadIdx.y;
    for (int j = 0; j < 4; ++j)
        tile[ty + j*8][tx] = src[(size_t)(by*32 + ty + j*8) * C + bx*32 + tx];
    __syncthreads();
    for (int j = 0; j < 4; ++j)
        dst[(size_t)(bx*32 + ty + j*8) * R + by*32 + tx] = __float2bfloat16(tile[tx][ty + j*8]);
}

// V transpose: qkv[m][1536 + h*64 + d] -> vT[bh][d][tok]; grid (20, 2, 192), block (32,8)
__global__ void v_tr(const bf16* __restrict__ qkv, bf16* __restrict__ vT) {
    __shared__ bf16 tile[32][33];
    int bhc = blockIdx.z;
    int b = bhc / NH, h = bhc - b * NH;
    int tt = blockIdx.x, dt = blockIdx.y;
    int tx = threadIdx.x, ty = threadIdx.y;
    for (int j = 0; j < 4; ++j) {
        int tok = tt*32 + ty + j*8;
        tile[ty + j*8][tx] = qkv[(size_t)(b*NN + tok)*QKVN + 2*DIM + h*HD + dt*32 + tx];
    }
    __syncthreads();
    for (int j = 0; j < 4; ++j) {
        int d = dt*32 + ty + j*8;
        vT[((size_t)bhc*HD + d)*NN + tt*32 + tx] = tile[tx][ty + j*8];
    }
}

// ---------------- GEMM: C = A @ B^T  (A [M][K] bf16, B [N][K] bf16) ----------------
// MODE 0: bf16 out row-major + bias.  MODE 1: fp32 out row-major + bias.
template<int MODE>
__global__ __launch_bounds__(256) void gemm_bt(
    const bf16* __restrict__ A, const bf16* __restrict__ B, const float* __restrict__ bias,
    int M, int N, int K,
    bf16* __restrict__ outb, float* __restrict__ outf)
{
    __shared__ __align__(16) bf16 As[128*32];
    __shared__ __align__(16) bf16 Bs[128*32];

    const int t = threadIdx.x;
    const int lane = t & 63, wave = t >> 6;
    const int l15 = lane & 15, quad = lane >> 4;
    const int wm = (wave >> 1) * 64, wn = (wave & 1) * 64;
    const int m0 = blockIdx.x * 128, n0 = blockIdx.y * 128;

    floatx4 acc[4][4];
    floatx4 zero = {0.f, 0.f, 0.f, 0.f};
    for (int i = 0; i < 4; ++i)
        for (int j = 0; j < 4; ++j)
            acc[i][j] = zero;

    for (int kk = 0; kk < K; kk += 32) {
        __syncthreads();
        // async stage A,B tiles (128x32 bf16 each): 2 chunks of 16 rows per wave per tile
        for (int s = 0; s < 2; ++s) {
            int cid = s * 256 + t;
            int row = cid >> 2;
            int c8  = (cid & 3) << 3;
            int lbase = (s * 256 + wave * 64) * 8;   // wave-uniform LDS base (elements)
            async_ld16(A + (size_t)(m0 + row) * K + kk + c8, As + lbase);
            async_ld16(B + (size_t)(n0 + row) * K + kk + c8, Bs + lbase);
        }
        __syncthreads();
        short8 af[4], bfv[4];
        for (int fm = 0; fm < 4; ++fm)
            af[fm] = *(const short8*)(As + (wm + fm*16 + l15) * 32 + quad * 8);
        for (int fn = 0; fn < 4; ++fn)
            bfv[fn] = *(const short8*)(Bs + (wn + fn*16 + l15) * 32 + quad * 8);
        for (int fm = 0; fm < 4; ++fm)
            for (int fn = 0; fn < 4; ++fn)
                acc[fm][fn] = mfma16(af[fm], bfv[fn], acc[fm][fn]);
    }

    // epilogue: C row-major, coalesced over l15
    for (int fm = 0; fm < 4; ++fm) {
        for (int fn = 0; fn < 4; ++fn) {
            int n = n0 + wn + fn*16 + l15;
            float bn = bias[n];
            for (int r = 0; r < 4; ++r) {
                int m = m0 + wm + fm*16 + quad*4 + r;
                float v = acc[fm][fn][r] + bn;
                if (MODE == 0) outb[(size_t)m * N + n] = __float2bfloat16(v);
                else           outf[(size_t)m * N + n] = v;
            }
        }
    }
}

// ---------------- fused attention ----------------
// grid (10, 192), block 256 (4 waves); wave handles 16 q rows, loops 20 key tiles of 32
__global__ __launch_bounds__(256) void attn_kernel(
    const bf16* __restrict__ qkv, const bf16* __restrict__ vT,
    const float* __restrict__ w2, bf16* __restrict__ ao)
{
    const int bh = blockIdx.y;
    const int b = bh / NH, h = bh - b * NH;
    const int wave = threadIdx.x >> 6;
    const int lane = threadIdx.x & 63;
    const int l15 = lane & 15, quad = lane >> 4;
    const int qrow0 = blockIdx.x * 64 + wave * 16;

    float w0 = w2[0], w1 = w2[1];
    float wmx = fmaxf(w0, w1);
    float e0 = __expf(w0 - wmx), e1 = __expf(w1 - wmx);
    float ws0 = e0 / (e0 + e1), ws1 = 1.0f - ws0;

    const bf16* qb = qkv + h * HD;              // q at col offset h*64
    const bf16* kb = qkv + DIM + h * HD;        // k at col offset 768 + h*64
    const bf16* vb = vT + (size_t)bh * HD * NN;
    const size_t rs = QKVN;                      // row stride in qkv

    short8 aq0 = *(const short8*)(qb + (size_t)(b*NN + qrow0 + l15) * rs + quad * 8);
    short8 aq1 = *(const short8*)(qb + (size_t)(b*NN + qrow0 + l15) * rs + 32 + quad * 8);

    floatx4 zero = {0.f, 0.f, 0.f, 0.f};
    floatx4 accS[4], accR[4];
    for (int i = 0; i < 4; ++i) { accS[i] = zero; accR[i] = zero; }
    float mrow[4], lrow[4];
    for (int r = 0; r < 4; ++r) { mrow[r] = -__builtin_inff(); lrow[r] = 0.f; }

    __shared__ __align__(16) bf16 Ps[4][16*32];
    __shared__ __align__(16) bf16 Pr[4][16*32];

    for (int kt = 0; kt < 20; ++kt) {
        short8 bk0 = *(const short8*)(kb + (size_t)(b*NN + kt*32 + l15) * rs + quad * 8);
        short8 bk1 = *(const short8*)(kb + (size_t)(b*NN + kt*32 + l15) * rs + 32 + quad * 8);
        short8 bk2 = *(const short8*)(kb + (size_t)(b*NN + kt*32 + 16 + l15) * rs + quad * 8);
        short8 bk3 = *(const short8*)(kb + (size_t)(b*NN + kt*32 + 16 + l15) * rs + 32 + quad * 8);

        floatx4 s0 = zero, s1 = zero;
        s0 = mfma16(aq0, bk0, s0);
        s0 = mfma16(aq1, bk1, s0);
        s1 = mfma16(aq0, bk2, s1);
        s1 = mfma16(aq1, bk3, s1);
        for (int r = 0; r < 4; ++r) { s0[r] *= SCALE; s1[r] *= SCALE; }

        // row max across the 16 lanes of each quad group
        float mt[4];
        for (int r = 0; r < 4; ++r) mt[r] = fmaxf(s0[r], s1[r]);
        for (int msk = 1; msk < 16; msk <<= 1)
            for (int r = 0; r < 4; ++r)
                mt[r] = fmaxf(mt[r], __shfl_xor(mt[r], msk));

        float al[4], ps0[4], ps1[4], pr0[4], pr1[4], rsum[4];
        for (int r = 0; r < 4; ++r) {
            float mn = fmaxf(mrow[r], mt[r]);
            al[r] = __expf(mrow[r] - mn);
            mrow[r] = mn;
            ps0[r] = __expf(s0[r] - mn);
            ps1[r] = __expf(s1[r] - mn);
            rsum[r] = ps0[r] + ps1[r];
            pr0[r] = s0[r] > 0.f ? s0[r] * s0[r] : 0.f;
            pr1[r] = s1[r] > 0.f ? s1[r] * s1[r] : 0.f;
        }
        for (int msk = 1; msk < 16; msk <<= 1)
            for (int r = 0; r < 4; ++r)
                rsum[r] += __shfl_xor(rsum[r], msk);
        for (int r = 0; r < 4; ++r) lrow[r] = lrow[r] * al[r] + rsum[r];
        for (int dt = 0; dt < 4; ++dt)
            for (int r = 0; r < 4; ++r)
                accS[dt][r] *= al[r];

        // C-frag -> A-frag transpose through per-wave LDS (no barrier needed:
        // buffers are per-wave and LDS ops complete in order within a wave)
        for (int r = 0; r < 4; ++r) {
            Ps[wave][(quad*4 + r) * 32 + l15]      = __float2bfloat16(ps0[r]);
            Ps[wave][(quad*4 + r) * 32 + 16 + l15] = __float2bfloat16(ps1[r]);
            Pr[wave][(quad*4 + r) * 32 + l15]      = __float2bfloat16(pr0[r]);
            Pr[wave][(quad*4 + r) * 32 + 16 + l15] = __float2bfloat16(pr1[r]);
        }
        short8 paS = *(const short8*)(&Ps[wave][l15 * 32 + quad * 8]);
        short8 paR = *(const short8*)(&Pr[wave][l15 * 32 + quad * 8]);

        for (int dt = 0; dt < 4; ++dt) {
            short8 bv = *(const short8*)(vb + (dt*16 + l15) * NN + kt*32 + quad * 8);
            accS[dt] = mfma16(paS, bv, accS[dt]);
            accR[dt] = mfma16(paR, bv, accR[dt]);
        }
    }

    float inv[4];
    for (int r = 0; r < 4; ++r) inv[r] = 1.0f / lrow[r];
    for (int dt = 0; dt < 4; ++dt) {
        for (int r = 0; r < 4; ++r) {
            float v = ws0 * accS[dt][r] * inv[r] + ws1 * accR[dt][r];
            int tok = qrow0 + quad*4 + r;
            ao[((size_t)(b * NN + tok)) * DIM + h * HD + dt*16 + l15] = __float2bfloat16(v);
        }
    }
}

// ---------------- launch ----------------

extern "C" void kernel_launch(void* const* d_in, const int* in_sizes, int n_in,
                              void* d_out, int out_size, void* d_ws, size_t ws_size,
                              hipStream_t stream) {
    const float* x      = (const float*)d_in[0];
    const float* qkv_w  = (const float*)d_in[1];
    const float* qkv_b  = (const float*)d_in[2];
    const float* proj_w = (const float*)d_in[3];
    const float* proj_b = (const float*)d_in[4];
    const float* w2     = (const float*)d_in[5];
    float* out = (float*)d_out;

    bf16* xb   = (bf16*)d_ws;                       // 10240*768   (reused as ao later)
    bf16* qwT  = xb   + (size_t)MROWS * DIM;        // 2304*768
    bf16* pwT  = qwT  + (size_t)QKVN * DIM;         // 768*768
    bf16* qkvb = pwT  + (size_t)DIM * DIM;          // 10240*2304
    bf16* vT   = qkvb + (size_t)MROWS * QKVN;       // 192*64*640
    bf16* ao   = xb;                                 // alias: xb dead after qkv gemm

    cvt_x<<<(MROWS * DIM / 4 + 255) / 256, 256, 0, stream>>>(x, xb, MROWS * DIM / 4);
    tr_cvt<<<dim3(QKVN / 32, DIM / 32), dim3(32, 8), 0, stream>>>(qkv_w, qwT, DIM, QKVN);
    tr_cvt<<<dim3(DIM / 32, DIM / 32), dim3(32, 8), 0, stream>>>(proj_w, pwT, DIM, DIM);

    gemm_bt<0><<<dim3(MROWS / 128, QKVN / 128), 256, 0, stream>>>(
        xb, qwT, qkv_b, MROWS, QKVN, DIM, qkvb, nullptr);

    v_tr<<<dim3(NN / 32, HD / 32, BH), dim3(32, 8), 0, stream>>>(qkvb, vT);

    attn_kernel<<<dim3(NN / 64, BH), 256, 0, stream>>>(qkvb, vT, w2, ao);

    gemm_bt<1><<<dim3(MROWS / 128, DIM / 128), 256, 0, stream>>>(
        ao, pwT, proj_b, MROWS, DIM, DIM, nullptr, out);
}

// Round 3
// 254.170 us; speedup vs baseline: 2.6115x; 1.3188x over previous
//
#include <hip/hip_runtime.h>
#include <hip/hip_bf16.h>

typedef __attribute__((ext_vector_type(8))) short short8;
typedef __attribute__((ext_vector_type(4))) float floatx4;
typedef __hip_bfloat16 bf16;

#define DIM 768
#define NH 12
#define HD 64
#define BB 16
#define NN 640
#define BH (BB*NH)          // 192
#define MROWS (BB*NN)       // 10240
#define QKVN (3*DIM)        // 2304
#define SCALE 0.125f

__device__ __forceinline__ floatx4 mfma16(short8 a, short8 b, floatx4 c) {
    return __builtin_amdgcn_mfma_f32_16x16x32_bf16(a, b, c, 0, 0, 0);
}

// async global->LDS, 16B per lane; lds dest = wave-uniform base + lane*16
__device__ __forceinline__ void async_ld16(const bf16* g, bf16* l) {
    __builtin_amdgcn_global_load_lds(
        (const __attribute__((address_space(1))) void*)g,
        (__attribute__((address_space(3))) void*)l, 16, 0, 0);
}

__device__ __forceinline__ unsigned pack_bf2(float a, float b) {
    union { bf16 h; unsigned short u; } x, y;
    x.h = __float2bfloat16(a); y.h = __float2bfloat16(b);
    return (unsigned)x.u | ((unsigned)y.u << 16);
}

// ---------------- prep kernels ----------------

__global__ void cvt_x(const float* __restrict__ x, bf16* __restrict__ xb, int n4) {
    int i = blockIdx.x * blockDim.x + threadIdx.x;
    if (i >= n4) return;
    float4 v = ((const float4*)x)[i];
    bf16* p = xb + (size_t)i * 4;
    p[0] = __float2bfloat16(v.x);
    p[1] = __float2bfloat16(v.y);
    p[2] = __float2bfloat16(v.z);
    p[3] = __float2bfloat16(v.w);
}

// src [R][C] fp32 -> dst [C][R] bf16 ; grid (C/32, R/32), block (32,8)
__global__ void tr_cvt(const float* __restrict__ src, bf16* __restrict__ dst, int R, int C) {
    __shared__ float tile[32][33];
    int bx = blockIdx.x, by = blockIdx.y;
    int tx = threadIdx.x, ty = threadIdx.y;
    for (int j = 0; j < 4; ++j)
        tile[ty + j*8][tx] = src[(size_t)(by*32 + ty + j*8) * C + bx*32 + tx];
    __syncthreads();
    for (int j = 0; j < 4; ++j)
        dst[(size_t)(bx*32 + ty + j*8) * R + by*32 + tx] = __float2bfloat16(tile[tx][ty + j*8]);
}

// V transpose: qkv[m][1536 + h*64 + d] -> vT[bh][d][tok]; grid (20, 2, 192), block (32,8)
__global__ void v_tr(const bf16* __restrict__ qkv, bf16* __restrict__ vT) {
    __shared__ bf16 tile[32][33];
    int bhc = blockIdx.z;
    int b = bhc / NH, h = bhc - b * NH;
    int tt = blockIdx.x, dt = blockIdx.y;
    int tx = threadIdx.x, ty = threadIdx.y;
    for (int j = 0; j < 4; ++j) {
        int tok = tt*32 + ty + j*8;
        tile[ty + j*8][tx] = qkv[(size_t)(b*NN + tok)*QKVN + 2*DIM + h*HD + dt*32 + tx];
    }
    __syncthreads();
    for (int j = 0; j < 4; ++j) {
        int d = dt*32 + ty + j*8;
        vT[((size_t)bhc*HD + d)*NN + tt*32 + tx] = tile[tx][ty + j*8];
    }
}

// ---------------- GEMM: C = A @ B^T  (A [M][K] bf16, B [N][K] bf16) ----------------
// MODE 0: bf16 out row-major + bias (+ SCALE folded into q cols n<768).
// MODE 1: fp32 out row-major + bias.
template<int MODE>
__global__ __launch_bounds__(256) void gemm_bt(
    const bf16* __restrict__ A, const bf16* __restrict__ B, const float* __restrict__ bias,
    int M, int N, int K,
    bf16* __restrict__ outb, float* __restrict__ outf)
{
    __shared__ __align__(16) bf16 As[128*32];
    __shared__ __align__(16) bf16 Bs[128*32];

    const int t = threadIdx.x;
    const int lane = t & 63, wave = t >> 6;
    const int l15 = lane & 15, quad = lane >> 4;
    const int wm = (wave >> 1) * 64, wn = (wave & 1) * 64;
    const int m0 = blockIdx.x * 128, n0 = blockIdx.y * 128;

    floatx4 acc[4][4];
    floatx4 zero = {0.f, 0.f, 0.f, 0.f};
    for (int i = 0; i < 4; ++i)
        for (int j = 0; j < 4; ++j)
            acc[i][j] = zero;

    for (int kk = 0; kk < K; kk += 32) {
        __syncthreads();
        for (int s = 0; s < 2; ++s) {
            int cid = s * 256 + t;
            int row = cid >> 2;
            int c8  = (cid & 3) << 3;
            int lbase = (s * 256 + wave * 64) * 8;
            async_ld16(A + (size_t)(m0 + row) * K + kk + c8, As + lbase);
            async_ld16(B + (size_t)(n0 + row) * K + kk + c8, Bs + lbase);
        }
        __syncthreads();
        short8 af[4], bfv[4];
        for (int fm = 0; fm < 4; ++fm)
            af[fm] = *(const short8*)(As + (wm + fm*16 + l15) * 32 + quad * 8);
        for (int fn = 0; fn < 4; ++fn)
            bfv[fn] = *(const short8*)(Bs + (wn + fn*16 + l15) * 32 + quad * 8);
        for (int fm = 0; fm < 4; ++fm)
            for (int fn = 0; fn < 4; ++fn)
                acc[fm][fn] = mfma16(af[fm], bfv[fn], acc[fm][fn]);
    }

    for (int fm = 0; fm < 4; ++fm) {
        for (int fn = 0; fn < 4; ++fn) {
            int n = n0 + wn + fn*16 + l15;
            float bn = bias[n];
            for (int r = 0; r < 4; ++r) {
                int m = m0 + wm + fm*16 + quad*4 + r;
                float v = acc[fm][fn][r] + bn;
                if (MODE == 0) {
                    if (n < DIM) v *= SCALE;   // pre-scale q
                    outb[(size_t)m * N + n] = __float2bfloat16(v);
                } else {
                    outf[(size_t)m * N + n] = v;
                }
            }
        }
    }
}

// ---------------- fused attention v2 ----------------
// grid (10, 192), block 256 (4 waves); wave handles 16 q rows.
// S^T formulation (K as A-operand): lane's C-frag column = one q row -> scalar row-sum.
// No max subtraction (|logits| << 88). K/V tiles LDS-staged, double-buffered.
__global__ __launch_bounds__(256) void attn_kernel(
    const bf16* __restrict__ qkv, const bf16* __restrict__ vT,
    const float* __restrict__ w2, bf16* __restrict__ ao)
{
    const int bh = blockIdx.y;
    const int b = bh / NH, h = bh - b * NH;
    const int t = threadIdx.x;
    const int wave = t >> 6;
    const int lane = t & 63;
    const int l15 = lane & 15, quad = lane >> 4;
    const int qrow0 = blockIdx.x * 64 + wave * 16;

    float w0 = w2[0], w1 = w2[1];
    float wmx = fmaxf(w0, w1);
    float e0 = __expf(w0 - wmx), e1 = __expf(w1 - wmx);
    float ws0 = e0 / (e0 + e1), ws1 = 1.0f - ws0;

    // K tile [32 tok][64 d] with chunk-xor swizzle; V tile [64 d][32 tok]
    __shared__ __align__(16) bf16 Kb[2][32*64];
    __shared__ __align__(16) bf16 Vb[2][64*32];
    __shared__ __align__(16) bf16 Ps[4][16*40];   // stride 40: pad for bank spread
    __shared__ __align__(16) bf16 Pr[4][16*40];

    const bf16* kg = qkv + (size_t)(b*NN)*QKVN + DIM + h*HD;
    const bf16* vg = vT + (size_t)bh * HD * NN;

    // Q fragments (B-operand: lane n=l15 -> q row, k=quad*8+j -> d)
    const bf16* qrow = qkv + (size_t)(b*NN + qrow0 + l15) * QKVN + h*HD;
    short8 aq0 = *(const short8*)(qrow + quad*8);
    short8 aq1 = *(const short8*)(qrow + 32 + quad*8);

    // staging address components (per thread)
    const int krow = t >> 3;
    const int kcg  = ((t & 7) ^ (krow & 7)) * 8;   // swizzled K chunk
    const int vrow = t >> 2;
    const int vcg  = (t & 3) * 8;

    // prologue: stage kt=0 into buf 0
    async_ld16(kg + (size_t)krow * QKVN + kcg, &Kb[0][wave*512]);
    async_ld16(vg + (size_t)vrow * NN + vcg,   &Vb[0][wave*512]);

    floatx4 zero = {0.f, 0.f, 0.f, 0.f};
    floatx4 accS[4], accR[4];
    for (int i = 0; i < 4; ++i) { accS[i] = zero; accR[i] = zero; }
    float lsum = 0.f;

    const int chLo = (quad ^ (l15 & 7)) * 8;       // swizzled chunk for d 0..31
    const int chHi = chLo ^ 32;                    // (chunk^4)*8

    for (int kt = 0; kt < 20; ++kt) {
        const int cur = kt & 1;
        // barrier: drains prefetch (compiler emits vmcnt(0) before s_barrier) and
        // ensures all waves done reading the buffer we're about to overwrite.
        __syncthreads();
        if (kt + 1 < 20) {
            async_ld16(kg + (size_t)((kt+1)*32 + krow) * QKVN + kcg, &Kb[cur^1][wave*512]);
            async_ld16(vg + (size_t)vrow * NN + (kt+1)*32 + vcg,     &Vb[cur^1][wave*512]);
        }

        const bf16* Kc = Kb[cur];
        short8 ak0lo = *(const short8*)(Kc + l15*64 + chLo);
        short8 ak0hi = *(const short8*)(Kc + l15*64 + chHi);
        short8 ak1lo = *(const short8*)(Kc + (16 + l15)*64 + chLo);
        short8 ak1hi = *(const short8*)(Kc + (16 + l15)*64 + chHi);

        // V B-frags (independent: issue early)
        const bf16* Vc = Vb[cur];
        short8 bv[4];
        for (int dt = 0; dt < 4; ++dt)
            bv[dt] = *(const short8*)(Vc + (dt*16 + l15)*32 + quad*8);

        floatx4 s0 = zero, s1 = zero;                 // S^T: row=kc, col=q
        s0 = mfma16(ak0lo, aq0, s0);
        s0 = mfma16(ak0hi, aq1, s0);
        s1 = mfma16(ak1lo, aq0, s1);
        s1 = mfma16(ak1hi, aq1, s1);

        float ex0[4], ex1[4], rq0[4], rq1[4];
        for (int r = 0; r < 4; ++r) {
            ex0[r] = __expf(s0[r]);
            ex1[r] = __expf(s1[r]);
            float m0 = fmaxf(s0[r], 0.f), m1 = fmaxf(s1[r], 0.f);
            rq0[r] = m0 * m0;
            rq1[r] = m1 * m1;
            lsum += ex0[r] + ex1[r];
        }

        // P transpose: store as [16 q][32 kc] (stride 40) -> A-frag reads contiguous
        unsigned* PsW = (unsigned*)&Ps[wave][0];
        unsigned* PrW = (unsigned*)&Pr[wave][0];
        int wb = l15*20 + quad*2;
        PsW[wb]     = pack_bf2(ex0[0], ex0[1]);
        PsW[wb + 1] = pack_bf2(ex0[2], ex0[3]);
        PsW[wb + 8] = pack_bf2(ex1[0], ex1[1]);
        PsW[wb + 9] = pack_bf2(ex1[2], ex1[3]);
        PrW[wb]     = pack_bf2(rq0[0], rq0[1]);
        PrW[wb + 1] = pack_bf2(rq0[2], rq0[3]);
        PrW[wb + 8] = pack_bf2(rq1[0], rq1[1]);
        PrW[wb + 9] = pack_bf2(rq1[2], rq1[3]);

        short8 paS = *(const short8*)(&Ps[wave][l15*40 + quad*8]);
        short8 paR = *(const short8*)(&Pr[wave][l15*40 + quad*8]);

        for (int dt = 0; dt < 4; ++dt) {
            accS[dt] = mfma16(paS, bv[dt], accS[dt]);
            accR[dt] = mfma16(paR, bv[dt], accR[dt]);
        }
    }

    // row-sum: reduce across quads (lanes with same l15)
    lsum += __shfl_xor(lsum, 16);
    lsum += __shfl_xor(lsum, 32);
    float invq[4];
    for (int r = 0; r < 4; ++r)
        invq[r] = 1.0f / __shfl(lsum, quad*4 + r);   // lanes 0..15 hold sums for q=l15

    for (int dt = 0; dt < 4; ++dt) {
        for (int r = 0; r < 4; ++r) {
            float v = ws0 * accS[dt][r] * invq[r] + ws1 * accR[dt][r];
            int tok = qrow0 + quad*4 + r;
            ao[((size_t)(b * NN + tok)) * DIM + h * HD + dt*16 + l15] = __float2bfloat16(v);
        }
    }
}

// ---------------- launch ----------------

extern "C" void kernel_launch(void* const* d_in, const int* in_sizes, int n_in,
                              void* d_out, int out_size, void* d_ws, size_t ws_size,
                              hipStream_t stream) {
    const float* x      = (const float*)d_in[0];
    const float* qkv_w  = (const float*)d_in[1];
    const float* qkv_b  = (const float*)d_in[2];
    const float* proj_w = (const float*)d_in[3];
    const float* proj_b = (const float*)d_in[4];
    const float* w2     = (const float*)d_in[5];
    float* out = (float*)d_out;

    bf16* xb   = (bf16*)d_ws;                       // 10240*768   (reused as ao later)
    bf16* qwT  = xb   + (size_t)MROWS * DIM;        // 2304*768
    bf16* pwT  = qwT  + (size_t)QKVN * DIM;         // 768*768
    bf16* qkvb = pwT  + (size_t)DIM * DIM;          // 10240*2304
    bf16* vT   = qkvb + (size_t)MROWS * QKVN;       // 192*64*640
    bf16* ao   = xb;                                 // alias: xb dead after qkv gemm

    cvt_x<<<(MROWS * DIM / 4 + 255) / 256, 256, 0, stream>>>(x, xb, MROWS * DIM / 4);
    tr_cvt<<<dim3(QKVN / 32, DIM / 32), dim3(32, 8), 0, stream>>>(qkv_w, qwT, DIM, QKVN);
    tr_cvt<<<dim3(DIM / 32, DIM / 32), dim3(32, 8), 0, stream>>>(proj_w, pwT, DIM, DIM);

    gemm_bt<0><<<dim3(MROWS / 128, QKVN / 128), 256, 0, stream>>>(
        xb, qwT, qkv_b, MROWS, QKVN, DIM, qkvb, nullptr);

    v_tr<<<dim3(NN / 32, HD / 32, BH), dim3(32, 8), 0, stream>>>(qkvb, vT);

    attn_kernel<<<dim3(NN / 64, BH), 256, 0, stream>>>(qkvb, vT, w2, ao);

    gemm_bt<1><<<dim3(MROWS / 128, DIM / 128), 256, 0, stream>>>(
        ao, pwT, proj_b, MROWS, DIM, DIM, nullptr, out);
}

// Round 4
// 248.606 us; speedup vs baseline: 2.6700x; 1.0224x over previous
//
#include <hip/hip_runtime.h>
#include <hip/hip_bf16.h>

typedef __attribute__((ext_vector_type(8))) short short8;
typedef __attribute__((ext_vector_type(4))) float floatx4;
typedef __hip_bfloat16 bf16;

#define DIM 768
#define NH 12
#define HD 64
#define BB 16
#define NN 640
#define BH (BB*NH)          // 192
#define MROWS (BB*NN)       // 10240
#define QKVN (3*DIM)        // 2304
#define SCALE 0.125f

__device__ __forceinline__ floatx4 mfma16(short8 a, short8 b, floatx4 c) {
    return __builtin_amdgcn_mfma_f32_16x16x32_bf16(a, b, c, 0, 0, 0);
}

// async global->LDS, 16B per lane; lds dest = wave-uniform base + lane*16
__device__ __forceinline__ void async_ld16(const bf16* g, bf16* l) {
    __builtin_amdgcn_global_load_lds(
        (const __attribute__((address_space(1))) void*)g,
        (__attribute__((address_space(3))) void*)l, 16, 0, 0);
}

__device__ __forceinline__ unsigned pack_bf2(float a, float b) {
    union { bf16 h; unsigned short u; } x, y;
    x.h = __float2bfloat16(a); y.h = __float2bfloat16(b);
    return (unsigned)x.u | ((unsigned)y.u << 16);
}

// ---------------- prep kernels ----------------

__global__ void cvt_x(const float* __restrict__ x, bf16* __restrict__ xb, int n4) {
    int i = blockIdx.x * blockDim.x + threadIdx.x;
    if (i >= n4) return;
    float4 v = ((const float4*)x)[i];
    bf16* p = xb + (size_t)i * 4;
    p[0] = __float2bfloat16(v.x);
    p[1] = __float2bfloat16(v.y);
    p[2] = __float2bfloat16(v.z);
    p[3] = __float2bfloat16(v.w);
}

// src [R][C] fp32 -> dst [C][R] bf16 ; grid (C/32, R/32), block (32,8)
__global__ void tr_cvt(const float* __restrict__ src, bf16* __restrict__ dst, int R, int C) {
    __shared__ float tile[32][33];
    int bx = blockIdx.x, by = blockIdx.y;
    int tx = threadIdx.x, ty = threadIdx.y;
    for (int j = 0; j < 4; ++j)
        tile[ty + j*8][tx] = src[(size_t)(by*32 + ty + j*8) * C + bx*32 + tx];
    __syncthreads();
    for (int j = 0; j < 4; ++j)
        dst[(size_t)(bx*32 + ty + j*8) * R + by*32 + tx] = __float2bfloat16(tile[tx][ty + j*8]);
}

// V transpose: qkv[m][1536 + h*64 + d] -> vT[bh][d][tok]; grid (20, 2, 192), block (32,8)
__global__ void v_tr(const bf16* __restrict__ qkv, bf16* __restrict__ vT) {
    __shared__ bf16 tile[32][33];
    int bhc = blockIdx.z;
    int b = bhc / NH, h = bhc - b * NH;
    int tt = blockIdx.x, dt = blockIdx.y;
    int tx = threadIdx.x, ty = threadIdx.y;
    for (int j = 0; j < 4; ++j) {
        int tok = tt*32 + ty + j*8;
        tile[ty + j*8][tx] = qkv[(size_t)(b*NN + tok)*QKVN + 2*DIM + h*HD + dt*32 + tx];
    }
    __syncthreads();
    for (int j = 0; j < 4; ++j) {
        int d = dt*32 + ty + j*8;
        vT[((size_t)bhc*HD + d)*NN + tt*32 + tx] = tile[tx][ty + j*8];
    }
}

// ---------------- GEMM: C = A @ B^T  (A [M][K] bf16, B [N][K] bf16) ----------------
// MODE 0: bf16 out row-major + bias (+ SCALE folded into q cols n<768).
// MODE 1: fp32 out row-major + bias.
template<int MODE>
__global__ __launch_bounds__(256) void gemm_bt(
    const bf16* __restrict__ A, const bf16* __restrict__ B, const float* __restrict__ bias,
    int M, int N, int K,
    bf16* __restrict__ outb, float* __restrict__ outf)
{
    __shared__ __align__(16) bf16 As[128*32];
    __shared__ __align__(16) bf16 Bs[128*32];

    const int t = threadIdx.x;
    const int lane = t & 63, wave = t >> 6;
    const int l15 = lane & 15, quad = lane >> 4;
    const int wm = (wave >> 1) * 64, wn = (wave & 1) * 64;
    const int m0 = blockIdx.x * 128, n0 = blockIdx.y * 128;

    floatx4 acc[4][4];
    floatx4 zero = {0.f, 0.f, 0.f, 0.f};
    for (int i = 0; i < 4; ++i)
        for (int j = 0; j < 4; ++j)
            acc[i][j] = zero;

    for (int kk = 0; kk < K; kk += 32) {
        __syncthreads();
        for (int s = 0; s < 2; ++s) {
            int cid = s * 256 + t;
            int row = cid >> 2;
            int c8  = (cid & 3) << 3;
            int lbase = (s * 256 + wave * 64) * 8;
            async_ld16(A + (size_t)(m0 + row) * K + kk + c8, As + lbase);
            async_ld16(B + (size_t)(n0 + row) * K + kk + c8, Bs + lbase);
        }
        __syncthreads();
        short8 af[4], bfv[4];
        for (int fm = 0; fm < 4; ++fm)
            af[fm] = *(const short8*)(As + (wm + fm*16 + l15) * 32 + quad * 8);
        for (int fn = 0; fn < 4; ++fn)
            bfv[fn] = *(const short8*)(Bs + (wn + fn*16 + l15) * 32 + quad * 8);
        for (int fm = 0; fm < 4; ++fm)
            for (int fn = 0; fn < 4; ++fn)
                acc[fm][fn] = mfma16(af[fm], bfv[fn], acc[fm][fn]);
    }

    for (int fm = 0; fm < 4; ++fm) {
        for (int fn = 0; fn < 4; ++fn) {
            int n = n0 + wn + fn*16 + l15;
            float bn = bias[n];
            for (int r = 0; r < 4; ++r) {
                int m = m0 + wm + fm*16 + quad*4 + r;
                float v = acc[fm][fn][r] + bn;
                if (MODE == 0) {
                    if (n < DIM) v *= SCALE;   // pre-scale q
                    outb[(size_t)m * N + n] = __float2bfloat16(v);
                } else {
                    outf[(size_t)m * N + n] = v;
                }
            }
        }
    }
}

// ---------------- fused attention v3 ----------------
// grid (192 bh, 10 qtile) -- bh fastest so a head's 10 q-tiles share an XCD
// (ids differ by 192 = 0 mod 8) and K/V re-reads hit the 4MB XCD L2.
// block 256 (4 waves); wave handles 16 q rows. S^T formulation.
__global__ __launch_bounds__(256) void attn_kernel(
    const bf16* __restrict__ qkv, const bf16* __restrict__ vT,
    const float* __restrict__ w2, bf16* __restrict__ ao)
{
    const int bh = blockIdx.x;
    const int b = bh / NH, h = bh - b * NH;
    const int t = threadIdx.x;
    const int wave = t >> 6;
    const int lane = t & 63;
    const int l15 = lane & 15, quad = lane >> 4;
    const int qrow0 = blockIdx.y * 64 + wave * 16;

    float w0 = w2[0], w1 = w2[1];
    float wmx = fmaxf(w0, w1);
    float e0 = __expf(w0 - wmx), e1 = __expf(w1 - wmx);
    float ws0 = e0 / (e0 + e1), ws1 = 1.0f - ws0;

    // K tile [32 tok][64 d] chunk-xor swizzled; V tile [64 d][32 tok] chunk-xor swizzled
    __shared__ __align__(16) bf16 Kb[2][32*64];
    __shared__ __align__(16) bf16 Vb[2][64*32];
    __shared__ __align__(16) bf16 Ps[4][16*40];
    __shared__ __align__(16) bf16 Pr[4][16*40];

    const bf16* kg = qkv + (size_t)(b*NN)*QKVN + DIM + h*HD;
    const bf16* vg = vT + (size_t)bh * HD * NN;

    // Q fragments (B-operand: lane n=l15 -> q row, k=quad*8+j -> d)
    const bf16* qrow = qkv + (size_t)(b*NN + qrow0 + l15) * QKVN + h*HD;
    short8 aq0 = *(const short8*)(qrow + quad*8);
    short8 aq1 = *(const short8*)(qrow + 32 + quad*8);

    // staging: K row = t>>3 (8 chunks/row), slot=t&7 holds chunk (t&7)^(row&7)
    const int krow = t >> 3;
    const int kcg  = ((t & 7) ^ (krow & 7)) * 8;
    // V row = t>>2 (4 chunks/row), slot=t&3 holds chunk (t&3)^((row>>1)&3)
    const int vrow = t >> 2;
    const int vcg  = ((t & 3) ^ ((t >> 3) & 3)) * 8;

    // running prefetch pointers (no per-iter 64-bit mul)
    const bf16* kgp = kg + (size_t)krow * QKVN + kcg;
    const bf16* vgp = vg + (size_t)vrow * NN + vcg;

    async_ld16(kgp, &Kb[0][wave*512]);
    async_ld16(vgp, &Vb[0][wave*512]);

    floatx4 zero = {0.f, 0.f, 0.f, 0.f};
    floatx4 accS[4], accR[4];
    for (int i = 0; i < 4; ++i) { accS[i] = zero; accR[i] = zero; }
    float lsum = 0.f;

    const int chLo = (quad ^ (l15 & 7)) * 8;       // K read slots (2-way, free)
    const int chHi = chLo ^ 32;
    const int vslotbase = ((l15 >> 1) & 3);        // V read slot = quad ^ ((r>>1)&3)

    // hoisted P-transpose LDS addresses
    unsigned* PsW = (unsigned*)&Ps[wave][0];
    unsigned* PrW = (unsigned*)&Pr[wave][0];
    const int wb = l15*20 + quad*2;
    const bf16* PsR = &Ps[wave][l15*40 + quad*8];
    const bf16* PrR = &Pr[wave][l15*40 + quad*8];

    for (int kt = 0; kt < 20; ++kt) {
        const int cur = kt & 1;
        __syncthreads();   // drains prefetch + protects buffer overwrite
        if (kt + 1 < 20) {
            kgp += 32 * QKVN;
            vgp += 32;
            async_ld16(kgp, &Kb[cur^1][wave*512]);
            async_ld16(vgp, &Vb[cur^1][wave*512]);
        }

        const bf16* Kc = Kb[cur];
        short8 ak0lo = *(const short8*)(Kc + l15*64 + chLo);
        short8 ak0hi = *(const short8*)(Kc + l15*64 + chHi);
        short8 ak1lo = *(const short8*)(Kc + (16 + l15)*64 + chLo);
        short8 ak1hi = *(const short8*)(Kc + (16 + l15)*64 + chHi);

        // V B-frags: row r = dt*16+l15, chunk quad at slot quad^((r>>1)&3)
        const bf16* Vc = Vb[cur];
        short8 bv[4];
        for (int dt = 0; dt < 4; ++dt)
            bv[dt] = *(const short8*)(Vc + (dt*16 + l15)*32 + (quad ^ vslotbase)*8);

        floatx4 s0 = zero, s1 = zero;                 // S^T: row=kc, col=q
        s0 = mfma16(ak0lo, aq0, s0);
        s0 = mfma16(ak0hi, aq1, s0);
        s1 = mfma16(ak1lo, aq0, s1);
        s1 = mfma16(ak1hi, aq1, s1);

        float ex0[4], ex1[4], rq0[4], rq1[4];
        for (int r = 0; r < 4; ++r) {
            ex0[r] = __expf(s0[r]);
            ex1[r] = __expf(s1[r]);
            float m0 = fmaxf(s0[r], 0.f), m1 = fmaxf(s1[r], 0.f);
            rq0[r] = m0 * m0;
            rq1[r] = m1 * m1;
            lsum += ex0[r] + ex1[r];
        }

        // P transpose: [16 q][32 kc] (stride 40)
        PsW[wb]     = pack_bf2(ex0[0], ex0[1]);
        PsW[wb + 1] = pack_bf2(ex0[2], ex0[3]);
        PsW[wb + 8] = pack_bf2(ex1[0], ex1[1]);
        PsW[wb + 9] = pack_bf2(ex1[2], ex1[3]);
        PrW[wb]     = pack_bf2(rq0[0], rq0[1]);
        PrW[wb + 1] = pack_bf2(rq0[2], rq0[3]);
        PrW[wb + 8] = pack_bf2(rq1[0], rq1[1]);
        PrW[wb + 9] = pack_bf2(rq1[2], rq1[3]);

        short8 paS = *(const short8*)PsR;
        short8 paR = *(const short8*)PrR;

        for (int dt = 0; dt < 4; ++dt) {
            accS[dt] = mfma16(paS, bv[dt], accS[dt]);
            accR[dt] = mfma16(paR, bv[dt], accR[dt]);
        }
    }

    lsum += __shfl_xor(lsum, 16);
    lsum += __shfl_xor(lsum, 32);
    float invq[4];
    for (int r = 0; r < 4; ++r)
        invq[r] = 1.0f / __shfl(lsum, quad*4 + r);

    for (int dt = 0; dt < 4; ++dt) {
        for (int r = 0; r < 4; ++r) {
            float v = ws0 * accS[dt][r] * invq[r] + ws1 * accR[dt][r];
            int tok = qrow0 + quad*4 + r;
            ao[((size_t)(b * NN + tok)) * DIM + h * HD + dt*16 + l15] = __float2bfloat16(v);
        }
    }
}

// ---------------- launch ----------------

extern "C" void kernel_launch(void* const* d_in, const int* in_sizes, int n_in,
                              void* d_out, int out_size, void* d_ws, size_t ws_size,
                              hipStream_t stream) {
    const float* x      = (const float*)d_in[0];
    const float* qkv_w  = (const float*)d_in[1];
    const float* qkv_b  = (const float*)d_in[2];
    const float* proj_w = (const float*)d_in[3];
    const float* proj_b = (const float*)d_in[4];
    const float* w2     = (const float*)d_in[5];
    float* out = (float*)d_out;

    bf16* xb   = (bf16*)d_ws;                       // 10240*768   (reused as ao later)
    bf16* qwT  = xb   + (size_t)MROWS * DIM;        // 2304*768
    bf16* pwT  = qwT  + (size_t)QKVN * DIM;         // 768*768
    bf16* qkvb = pwT  + (size_t)DIM * DIM;          // 10240*2304
    bf16* vT   = qkvb + (size_t)MROWS * QKVN;       // 192*64*640
    bf16* ao   = xb;                                 // alias: xb dead after qkv gemm

    cvt_x<<<(MROWS * DIM / 4 + 255) / 256, 256, 0, stream>>>(x, xb, MROWS * DIM / 4);
    tr_cvt<<<dim3(QKVN / 32, DIM / 32), dim3(32, 8), 0, stream>>>(qkv_w, qwT, DIM, QKVN);
    tr_cvt<<<dim3(DIM / 32, DIM / 32), dim3(32, 8), 0, stream>>>(proj_w, pwT, DIM, DIM);

    gemm_bt<0><<<dim3(MROWS / 128, QKVN / 128), 256, 0, stream>>>(
        xb, qwT, qkv_b, MROWS, QKVN, DIM, qkvb, nullptr);

    v_tr<<<dim3(NN / 32, HD / 32, BH), dim3(32, 8), 0, stream>>>(qkvb, vT);

    attn_kernel<<<dim3(BH, NN / 64), 256, 0, stream>>>(qkvb, vT, w2, ao);

    gemm_bt<1><<<dim3(MROWS / 128, DIM / 128), 256, 0, stream>>>(
        ao, pwT, proj_b, MROWS, DIM, DIM, nullptr, out);
}

// Round 5
// 247.410 us; speedup vs baseline: 2.6829x; 1.0048x over previous
//
#include <hip/hip_runtime.h>
#include <hip/hip_bf16.h>

typedef __attribute__((ext_vector_type(8))) short short8;
typedef __attribute__((ext_vector_type(4))) float floatx4;
typedef __hip_bfloat16 bf16;

#define DIM 768
#define NH 12
#define HD 64
#define BB 16
#define NN 640
#define BH (BB*NH)          // 192
#define MROWS (BB*NN)       // 10240
#define QKVN (3*DIM)        // 2304
#define SCALE 0.125f
#define QSCALE 0.18033688011113205f   // 0.125 * log2(e)
#define LN2SQ 0.4804530139182014f     // ln(2)^2

__device__ __forceinline__ floatx4 mfma16(short8 a, short8 b, floatx4 c) {
    return __builtin_amdgcn_mfma_f32_16x16x32_bf16(a, b, c, 0, 0, 0);
}

// async global->LDS, 16B per lane; lds dest = wave-uniform base + lane*16
__device__ __forceinline__ void async_ld16(const bf16* g, bf16* l) {
    __builtin_amdgcn_global_load_lds(
        (const __attribute__((address_space(1))) void*)g,
        (__attribute__((address_space(3))) void*)l, 16, 0, 0);
}

// truncate two f32 to bf16 and pack: lo16 = a, hi16 = b  (one v_perm_b32)
__device__ __forceinline__ unsigned pack_trunc(float a, float b) {
    return __builtin_amdgcn_perm(__float_as_uint(b), __float_as_uint(a), 0x07060302u);
}

__device__ __forceinline__ float fexp2(float x) {
#if __has_builtin(__builtin_amdgcn_exp2f)
    return __builtin_amdgcn_exp2f(x);
#else
    return exp2f(x);
#endif
}

// ---------------- prep kernels ----------------

__global__ void cvt_x(const float* __restrict__ x, bf16* __restrict__ xb, int n4) {
    int i = blockIdx.x * blockDim.x + threadIdx.x;
    if (i >= n4) return;
    float4 v = ((const float4*)x)[i];
    bf16* p = xb + (size_t)i * 4;
    p[0] = __float2bfloat16(v.x);
    p[1] = __float2bfloat16(v.y);
    p[2] = __float2bfloat16(v.z);
    p[3] = __float2bfloat16(v.w);
}

// src [R][C] fp32 -> dst [C][R] bf16 ; grid (C/32, R/32), block (32,8)
__global__ void tr_cvt(const float* __restrict__ src, bf16* __restrict__ dst, int R, int C) {
    __shared__ float tile[32][33];
    int bx = blockIdx.x, by = blockIdx.y;
    int tx = threadIdx.x, ty = threadIdx.y;
    for (int j = 0; j < 4; ++j)
        tile[ty + j*8][tx] = src[(size_t)(by*32 + ty + j*8) * C + bx*32 + tx];
    __syncthreads();
    for (int j = 0; j < 4; ++j)
        dst[(size_t)(bx*32 + ty + j*8) * R + by*32 + tx] = __float2bfloat16(tile[tx][ty + j*8]);
}

// V transpose: qkv[m][1536 + h*64 + d] -> vT[bh][d][tok]; grid (20, 2, 192), block (32,8)
__global__ void v_tr(const bf16* __restrict__ qkv, bf16* __restrict__ vT) {
    __shared__ bf16 tile[32][33];
    int bhc = blockIdx.z;
    int b = bhc / NH, h = bhc - b * NH;
    int tt = blockIdx.x, dt = blockIdx.y;
    int tx = threadIdx.x, ty = threadIdx.y;
    for (int j = 0; j < 4; ++j) {
        int tok = tt*32 + ty + j*8;
        tile[ty + j*8][tx] = qkv[(size_t)(b*NN + tok)*QKVN + 2*DIM + h*HD + dt*32 + tx];
    }
    __syncthreads();
    for (int j = 0; j < 4; ++j) {
        int d = dt*32 + ty + j*8;
        vT[((size_t)bhc*HD + d)*NN + tt*32 + tx] = tile[tx][ty + j*8];
    }
}

// ---------------- GEMM: C = A @ B^T  (A [M][K] bf16, B [N][K] bf16) ----------------
// grid (N/128, M/128): n-tile FASTEST so consecutive blocks share the A row-panel
// and each XCD's L2 working set is B (3.5 MB < 4 MB) not A (15.7 MB).
// MODE 0: bf16 out row-major + bias (+ QSCALE folded into q cols n<768).
// MODE 1: fp32 out row-major + bias.
template<int MODE>
__global__ __launch_bounds__(256) void gemm_bt(
    const bf16* __restrict__ A, const bf16* __restrict__ B, const float* __restrict__ bias,
    int M, int N, int K,
    bf16* __restrict__ outb, float* __restrict__ outf)
{
    __shared__ __align__(16) bf16 As[128*32];
    __shared__ __align__(16) bf16 Bs[128*32];

    const int t = threadIdx.x;
    const int lane = t & 63, wave = t >> 6;
    const int l15 = lane & 15, quad = lane >> 4;
    const int wm = (wave >> 1) * 64, wn = (wave & 1) * 64;
    const int m0 = blockIdx.y * 128, n0 = blockIdx.x * 128;

    floatx4 acc[4][4];
    floatx4 zero = {0.f, 0.f, 0.f, 0.f};
    for (int i = 0; i < 4; ++i)
        for (int j = 0; j < 4; ++j)
            acc[i][j] = zero;

    for (int kk = 0; kk < K; kk += 32) {
        __syncthreads();
        for (int s = 0; s < 2; ++s) {
            int cid = s * 256 + t;
            int row = cid >> 2;
            int c8  = (cid & 3) << 3;
            int lbase = (s * 256 + wave * 64) * 8;
            async_ld16(A + (size_t)(m0 + row) * K + kk + c8, As + lbase);
            async_ld16(B + (size_t)(n0 + row) * K + kk + c8, Bs + lbase);
        }
        __syncthreads();
        short8 af[4], bfv[4];
        for (int fm = 0; fm < 4; ++fm)
            af[fm] = *(const short8*)(As + (wm + fm*16 + l15) * 32 + quad * 8);
        for (int fn = 0; fn < 4; ++fn)
            bfv[fn] = *(const short8*)(Bs + (wn + fn*16 + l15) * 32 + quad * 8);
        for (int fm = 0; fm < 4; ++fm)
            for (int fn = 0; fn < 4; ++fn)
                acc[fm][fn] = mfma16(af[fm], bfv[fn], acc[fm][fn]);
    }

    for (int fm = 0; fm < 4; ++fm) {
        for (int fn = 0; fn < 4; ++fn) {
            int n = n0 + wn + fn*16 + l15;
            float bn = bias[n];
            for (int r = 0; r < 4; ++r) {
                int m = m0 + wm + fm*16 + quad*4 + r;
                float v = acc[fm][fn][r] + bn;
                if (MODE == 0) {
                    if (n < DIM) v *= QSCALE;   // pre-scale q (incl. log2e for exp2)
                    outb[(size_t)m * N + n] = __float2bfloat16(v);
                } else {
                    outf[(size_t)m * N + n] = v;
                }
            }
        }
    }
}

// ---------------- fused attention v4 ----------------
// grid (192 bh, 10 qtile): bh fastest so a head's q-tiles share an XCD L2.
// block 256 (4 waves); wave handles 16 q rows. S^T formulation; s' = S*log2e
// (log2e folded into q), softmax via native exp2, relu^2 rescaled by ln2^2 at
// the epilogue. P packed to bf16 by truncation (v_perm), written as b64 pairs.
__global__ __launch_bounds__(256) void attn_kernel(
    const bf16* __restrict__ qkv, const bf16* __restrict__ vT,
    const float* __restrict__ w2, bf16* __restrict__ ao)
{
    const int bh = blockIdx.x;
    const int b = bh / NH, h = bh - b * NH;
    const int t = threadIdx.x;
    const int wave = t >> 6;
    const int lane = t & 63;
    const int l15 = lane & 15, quad = lane >> 4;
    const int qrow0 = blockIdx.y * 64 + wave * 16;

    float w0 = w2[0], w1 = w2[1];
    float wmx = fmaxf(w0, w1);
    float e0 = __expf(w0 - wmx), e1 = __expf(w1 - wmx);
    float ws0 = e0 / (e0 + e1);
    float ws1 = (1.0f - ws0) * LN2SQ;   // fold ln2^2 (relu^2 path computed on s*log2e)

    __shared__ __align__(16) bf16 Kb[2][32*64];
    __shared__ __align__(16) bf16 Vb[2][64*32];
    __shared__ __align__(16) bf16 Ps[4][16*40];
    __shared__ __align__(16) bf16 Pr[4][16*40];

    const bf16* kg = qkv + (size_t)(b*NN)*QKVN + DIM + h*HD;
    const bf16* vg = vT + (size_t)bh * HD * NN;

    const bf16* qrow = qkv + (size_t)(b*NN + qrow0 + l15) * QKVN + h*HD;
    short8 aq0 = *(const short8*)(qrow + quad*8);
    short8 aq1 = *(const short8*)(qrow + 32 + quad*8);

    const int krow = t >> 3;
    const int kcg  = ((t & 7) ^ (krow & 7)) * 8;
    const int vrow = t >> 2;
    const int vcg  = ((t & 3) ^ ((t >> 3) & 3)) * 8;

    const bf16* kgp = kg + (size_t)krow * QKVN + kcg;
    const bf16* vgp = vg + (size_t)vrow * NN + vcg;

    async_ld16(kgp, &Kb[0][wave*512]);
    async_ld16(vgp, &Vb[0][wave*512]);

    floatx4 zero = {0.f, 0.f, 0.f, 0.f};
    floatx4 accS[4], accR[4];
    for (int i = 0; i < 4; ++i) { accS[i] = zero; accR[i] = zero; }
    float lsum = 0.f;

    const int chLo = (quad ^ (l15 & 7)) * 8;
    const int chHi = chLo ^ 32;
    const int vslotbase = ((l15 >> 1) & 3);

    unsigned* PsW = (unsigned*)&Ps[wave][0];
    unsigned* PrW = (unsigned*)&Pr[wave][0];
    const int wb = l15*20 + quad*2;
    const bf16* PsR = &Ps[wave][l15*40 + quad*8];
    const bf16* PrR = &Pr[wave][l15*40 + quad*8];

#pragma unroll 2
    for (int kt = 0; kt < 20; ++kt) {
        const int cur = kt & 1;
        __syncthreads();   // drains prefetch + protects buffer overwrite
        if (kt + 1 < 20) {
            kgp += 32 * QKVN;
            vgp += 32;
            async_ld16(kgp, &Kb[cur^1][wave*512]);
            async_ld16(vgp, &Vb[cur^1][wave*512]);
        }

        const bf16* Kc = Kb[cur];
        short8 ak0lo = *(const short8*)(Kc + l15*64 + chLo);
        short8 ak0hi = *(const short8*)(Kc + l15*64 + chHi);
        short8 ak1lo = *(const short8*)(Kc + (16 + l15)*64 + chLo);
        short8 ak1hi = *(const short8*)(Kc + (16 + l15)*64 + chHi);

        const bf16* Vc = Vb[cur];
        short8 bv[4];
        for (int dt = 0; dt < 4; ++dt)
            bv[dt] = *(const short8*)(Vc + (dt*16 + l15)*32 + (quad ^ vslotbase)*8);

        floatx4 s0 = zero, s1 = zero;                 // S'^T = S^T * log2e
        s0 = mfma16(ak0lo, aq0, s0);
        s0 = mfma16(ak0hi, aq1, s0);
        s1 = mfma16(ak1lo, aq0, s1);
        s1 = mfma16(ak1hi, aq1, s1);

        float ex0[4], ex1[4], rq0[4], rq1[4];
        for (int r = 0; r < 4; ++r) {
            ex0[r] = fexp2(s0[r]);
            ex1[r] = fexp2(s1[r]);
            float m0 = fmaxf(s0[r], 0.f), m1 = fmaxf(s1[r], 0.f);
            rq0[r] = m0 * m0;
            rq1[r] = m1 * m1;
            lsum += ex0[r] + ex1[r];
        }

        // P transpose: [16 q][32 kc] (stride 40), b64 writes, v_perm trunc pack
        *(uint2*)(PsW + wb)     = make_uint2(pack_trunc(ex0[0], ex0[1]), pack_trunc(ex0[2], ex0[3]));
        *(uint2*)(PsW + wb + 8) = make_uint2(pack_trunc(ex1[0], ex1[1]), pack_trunc(ex1[2], ex1[3]));
        *(uint2*)(PrW + wb)     = make_uint2(pack_trunc(rq0[0], rq0[1]), pack_trunc(rq0[2], rq0[3]));
        *(uint2*)(PrW + wb + 8) = make_uint2(pack_trunc(rq1[0], rq1[1]), pack_trunc(rq1[2], rq1[3]));

        short8 paS = *(const short8*)PsR;
        short8 paR = *(const short8*)PrR;

        for (int dt = 0; dt < 4; ++dt) {
            accS[dt] = mfma16(paS, bv[dt], accS[dt]);
            accR[dt] = mfma16(paR, bv[dt], accR[dt]);
        }
    }

    lsum += __shfl_xor(lsum, 16);
    lsum += __shfl_xor(lsum, 32);
    float invq[4];
    for (int r = 0; r < 4; ++r)
        invq[r] = 1.0f / __shfl(lsum, quad*4 + r);

    for (int dt = 0; dt < 4; ++dt) {
        for (int r = 0; r < 4; ++r) {
            float v = ws0 * accS[dt][r] * invq[r] + ws1 * accR[dt][r];
            int tok = qrow0 + quad*4 + r;
            ao[((size_t)(b * NN + tok)) * DIM + h * HD + dt*16 + l15] = __float2bfloat16(v);
        }
    }
}

// ---------------- launch ----------------

extern "C" void kernel_launch(void* const* d_in, const int* in_sizes, int n_in,
                              void* d_out, int out_size, void* d_ws, size_t ws_size,
                              hipStream_t stream) {
    const float* x      = (const float*)d_in[0];
    const float* qkv_w  = (const float*)d_in[1];
    const float* qkv_b  = (const float*)d_in[2];
    const float* proj_w = (const float*)d_in[3];
    const float* proj_b = (const float*)d_in[4];
    const float* w2     = (const float*)d_in[5];
    float* out = (float*)d_out;

    bf16* xb   = (bf16*)d_ws;                       // 10240*768   (reused as ao later)
    bf16* qwT  = xb   + (size_t)MROWS * DIM;        // 2304*768
    bf16* pwT  = qwT  + (size_t)QKVN * DIM;         // 768*768
    bf16* qkvb = pwT  + (size_t)DIM * DIM;          // 10240*2304
    bf16* vT   = qkvb + (size_t)MROWS * QKVN;       // 192*64*640
    bf16* ao   = xb;                                 // alias: xb dead after qkv gemm

    cvt_x<<<(MROWS * DIM / 4 + 255) / 256, 256, 0, stream>>>(x, xb, MROWS * DIM / 4);
    tr_cvt<<<dim3(QKVN / 32, DIM / 32), dim3(32, 8), 0, stream>>>(qkv_w, qwT, DIM, QKVN);
    tr_cvt<<<dim3(DIM / 32, DIM / 32), dim3(32, 8), 0, stream>>>(proj_w, pwT, DIM, DIM);

    gemm_bt<0><<<dim3(QKVN / 128, MROWS / 128), 256, 0, stream>>>(
        xb, qwT, qkv_b, MROWS, QKVN, DIM, qkvb, nullptr);

    v_tr<<<dim3(NN / 32, HD / 32, BH), dim3(32, 8), 0, stream>>>(qkvb, vT);

    attn_kernel<<<dim3(BH, NN / 64), 256, 0, stream>>>(qkvb, vT, w2, ao);

    gemm_bt<1><<<dim3(DIM / 128, MROWS / 128), 256, 0, stream>>>(
        ao, pwT, proj_b, MROWS, DIM, DIM, nullptr, out);
}